// Round 3
// baseline (7298.939 us; speedup 1.0000x reference)
//
#include <hip/hip_runtime.h>
#include <hip/hip_bf16.h>

#define N_NODES 50000
#define NE      500000
#define HIDD    128
#define TDIM    32
#define NHEAD   4

__device__ __forceinline__ float leaky(float z) { return z >= 0.f ? z : 0.2f * z; }

// ---------------------------------------------------------------------------
// Kernel A: per-node projections for one direction.
//   sj[n][h] = sum_d leaky((x_src@Ws)[n][h,d]) * a_j[h][d]
//   si[n][h] = sum_d leaky((x_dst@Wd)[n][h,d]) * a_i[h][d]
//   V[n][:]  = (x_src@Wv)[n][:]
// block=256, 16 nodes/block, N divisible by 16 (50000 = 3125*16).
// ---------------------------------------------------------------------------
__global__ __launch_bounds__(256) void node_proj_kernel(
    const float* __restrict__ xsrc, const float* __restrict__ xdst,
    const float* __restrict__ Ws, const float* __restrict__ Wd,
    const float* __restrict__ Wv, const float* __restrict__ att,
    float* __restrict__ sj, float* __restrict__ si, float* __restrict__ V)
{
    __shared__ float xs[16][HIDD];
    __shared__ float xd[16][HIDD];
    const int t = threadIdx.x;
    const long node0 = (long)blockIdx.x * 16;

    for (int i = 0; i < 8; ++i) {
        int g = t + i * 256;            // 0..2047
        int nn = g >> 7, c = g & 127;
        xs[nn][c] = xsrc[(node0 + nn) * HIDD + c];
        xd[nn][c] = xdst[(node0 + nn) * HIDD + c];
    }
    __syncthreads();

    const int c = t & 127;
    const int np = t >> 7;              // which 8-node group
    const int h = c >> 5, dh = c & 31;

    for (int m = 0; m < 3; ++m) {
        const float* W = (m == 0) ? Ws : ((m == 1) ? Wd : Wv);
        const float (*X)[HIDD] = (m == 1) ? xd : xs;
        float acc[8];
        #pragma unroll
        for (int nn = 0; nn < 8; ++nn) acc[nn] = 0.f;
        for (int k = 0; k < HIDD; ++k) {
            float w = W[k * HIDD + c];        // coalesced across c
            #pragma unroll
            for (int nn = 0; nn < 8; ++nn) acc[nn] += X[np * 8 + nn][k] * w;
        }
        if (m < 2) {
            float coef = att[h * 96 + (m == 1 ? 32 : 0) + dh];
            float* outp = (m == 0) ? sj : si;
            #pragma unroll
            for (int nn = 0; nn < 8; ++nn) {
                float v = leaky(acc[nn]) * coef;
                #pragma unroll
                for (int off = 16; off > 0; off >>= 1) v += __shfl_down(v, off, 32);
                if (dh == 0) outp[(node0 + np * 8 + nn) * 4 + h] = v;
            }
        } else {
            #pragma unroll
            for (int nn = 0; nn < 8; ++nn)
                V[(node0 + np * 8 + nn) * HIDD + c] = acc[nn];
        }
    }
}

// ---------------------------------------------------------------------------
// Kernel B: per-edge logits + exp + segment-sum (no segment-max needed:
// logits are bounded, softmax is shift-invariant, so max-subtraction is a
// mathematical no-op here).  t_proj recomputed from LDS-resident Wt^T.
// ---------------------------------------------------------------------------
__global__ __launch_bounds__(256) void edge_logits_kernel(
    const int* __restrict__ ei, const float* __restrict__ tfeat,
    const float* __restrict__ Wt, const float* __restrict__ att,
    const float* __restrict__ sj, const float* __restrict__ si,
    float* __restrict__ exbuf, float* __restrict__ ssum)
{
    __shared__ float WtT[HIDD * TDIM];   // [d][k]
    __shared__ float attL[HIDD];
    const int t = threadIdx.x;
    for (int i = 0; i < 16; ++i) {
        int g = t + i * 256;             // 0..4095, Wt row-major [k][d]
        int k = g >> 7, d = g & 127;
        WtT[d * TDIM + k] = Wt[g];
    }
    if (t < HIDD) attL[t] = att[(t >> 5) * 96 + 64 + (t & 31)];
    __syncthreads();

    const long e = (long)blockIdx.x * 256 + t;
    if (e >= NE) return;
    const int src = ei[e], dst = ei[NE + e];

    float tt[TDIM];
    {
        const float4* tp = (const float4*)(tfeat + e * TDIM);
        #pragma unroll
        for (int i = 0; i < 8; ++i) {
            float4 q = tp[i];
            tt[4 * i + 0] = q.x; tt[4 * i + 1] = q.y;
            tt[4 * i + 2] = q.z; tt[4 * i + 3] = q.w;
        }
    }

    float st[4] = {0.f, 0.f, 0.f, 0.f};
    for (int d = 0; d < HIDD; ++d) {
        const float4* wp = (const float4*)&WtT[d * TDIM];
        float tpv = 0.f;
        #pragma unroll
        for (int kk = 0; kk < 8; ++kk) {
            float4 w = wp[kk];
            tpv += tt[kk * 4 + 0] * w.x + tt[kk * 4 + 1] * w.y
                 + tt[kk * 4 + 2] * w.z + tt[kk * 4 + 3] * w.w;
        }
        st[d >> 5] += leaky(tpv) * attL[d];
    }

    const float4 sj4 = ((const float4*)sj)[src];
    const float4 si4 = ((const float4*)si)[dst];
    float e0 = __expf(sj4.x + si4.x + st[0]);
    float e1 = __expf(sj4.y + si4.y + st[1]);
    float e2 = __expf(sj4.z + si4.z + st[2]);
    float e3 = __expf(sj4.w + si4.w + st[3]);
    ((float4*)exbuf)[e] = make_float4(e0, e1, e2, e3);
    float* sp = ssum + (long)dst * 4;
    unsafeAtomicAdd(sp + 0, e0);
    unsafeAtomicAdd(sp + 1, e1);
    unsafeAtomicAdd(sp + 2, e2);
    unsafeAtomicAdd(sp + 3, e3);
}

// ---------------------------------------------------------------------------
// Kernel C: per-edge message scatter:
//   alpha[h] = ex[e][h] / (s[dst][h] + 1e-16)
//   agg[dst][d] += (V[src][d] + t_proj[e][d]) * alpha[d/32]
// ---------------------------------------------------------------------------
__global__ __launch_bounds__(256) void edge_scatter_kernel(
    const int* __restrict__ ei, const float* __restrict__ tfeat,
    const float* __restrict__ Wt,
    const float* __restrict__ exbuf, const float* __restrict__ ssum,
    const float* __restrict__ V, float* __restrict__ agg)
{
    __shared__ float WtT[HIDD * TDIM];
    const int t = threadIdx.x;
    for (int i = 0; i < 16; ++i) {
        int g = t + i * 256;
        int k = g >> 7, d = g & 127;
        WtT[d * TDIM + k] = Wt[g];
    }
    __syncthreads();

    const long e = (long)blockIdx.x * 256 + t;
    if (e >= NE) return;
    const int src = ei[e], dst = ei[NE + e];

    float tt[TDIM];
    {
        const float4* tp = (const float4*)(tfeat + e * TDIM);
        #pragma unroll
        for (int i = 0; i < 8; ++i) {
            float4 q = tp[i];
            tt[4 * i + 0] = q.x; tt[4 * i + 1] = q.y;
            tt[4 * i + 2] = q.z; tt[4 * i + 3] = q.w;
        }
    }

    const float4 exv = ((const float4*)exbuf)[e];
    const float4 sv  = ((const float4*)ssum)[dst];
    float al[4] = { exv.x / (sv.x + 1e-16f), exv.y / (sv.y + 1e-16f),
                    exv.z / (sv.z + 1e-16f), exv.w / (sv.w + 1e-16f) };

    const float4* Vp = (const float4*)(V + (long)src * HIDD);
    float* aggp = agg + (long)dst * HIDD;

    for (int d0 = 0; d0 < HIDD; d0 += 4) {
        float4 v4 = Vp[d0 >> 2];
        float vj[4] = {v4.x, v4.y, v4.z, v4.w};
        float ah = al[d0 >> 5];
        #pragma unroll
        for (int j = 0; j < 4; ++j) {
            const float4* wp = (const float4*)&WtT[(d0 + j) * TDIM];
            float tpv = 0.f;
            #pragma unroll
            for (int kk = 0; kk < 8; ++kk) {
                float4 w = wp[kk];
                tpv += tt[kk * 4 + 0] * w.x + tt[kk * 4 + 1] * w.y
                     + tt[kk * 4 + 2] * w.z + tt[kk * 4 + 3] * w.w;
            }
            unsafeAtomicAdd(&aggp[d0 + j], (vj[j] + tpv) * ah);
        }
    }
}

// ---------------------------------------------------------------------------
// Kernel D: out = LayerNorm(h + agg @ Wout + bout) * lnw + lnb   (f32 out)
// block=256, 16 nodes/block.
// ---------------------------------------------------------------------------
__global__ __launch_bounds__(256) void out_kernel(
    const float* __restrict__ agg, const float* __restrict__ h,
    const float* __restrict__ Wout, const float* __restrict__ bout,
    const float* __restrict__ lnw, const float* __restrict__ lnb,
    float* __restrict__ out)
{
    __shared__ float ag[16][HIDD];
    __shared__ float red[2][2][2];
    const int t = threadIdx.x;
    const long node0 = (long)blockIdx.x * 16;

    for (int i = 0; i < 8; ++i) {
        int g = t + i * 256;
        int nn = g >> 7, c = g & 127;
        ag[nn][c] = agg[(node0 + nn) * HIDD + c];
    }
    __syncthreads();

    const int c = t & 127;
    const int np = t >> 7;
    const int wg = (t >> 6) & 1;        // wave index within node group

    float acc[8];
    #pragma unroll
    for (int nn = 0; nn < 8; ++nn) acc[nn] = 0.f;
    for (int k = 0; k < HIDD; ++k) {
        float w = Wout[k * HIDD + c];
        #pragma unroll
        for (int nn = 0; nn < 8; ++nn) acc[nn] += ag[np * 8 + nn][k] * w;
    }

    const float bo = bout[c];
    const float lw = lnw[c];
    const float lb = lnb[c];

    for (int nn = 0; nn < 8; ++nn) {
        long node = node0 + np * 8 + nn;
        float y = h[node * HIDD + c] + acc[nn] + bo;
        float s1 = y, s2 = y * y;
        #pragma unroll
        for (int off = 32; off > 0; off >>= 1) {
            s1 += __shfl_down(s1, off, 64);
            s2 += __shfl_down(s2, off, 64);
        }
        if ((t & 63) == 0) { red[np][wg][0] = s1; red[np][wg][1] = s2; }
        __syncthreads();
        float sum = red[np][0][0] + red[np][1][0];
        float sq  = red[np][0][1] + red[np][1][1];
        float mu  = sum * (1.f / 128.f);
        float var = sq * (1.f / 128.f) - mu * mu;
        float inv = rsqrtf(var + 1e-5f);
        out[node * HIDD + c] = (y - mu) * inv * lw + lb;
        __syncthreads();
    }
}

// ---------------------------------------------------------------------------
extern "C" void kernel_launch(void* const* d_in, const int* in_sizes, int n_in,
                              void* d_out, int out_size, void* d_ws, size_t ws_size,
                              hipStream_t stream)
{
    const float* h_user    = (const float*)d_in[0];
    const float* h_item    = (const float*)d_in[1];
    const int*   ei_ui     = (const int*)d_in[2];
    const float* t_ui      = (const float*)d_in[3];
    const int*   ei_iu     = (const int*)d_in[4];
    const float* t_iu      = (const float*)d_in[5];
    const float* W_src_ui  = (const float*)d_in[6];
    const float* W_dst_ui  = (const float*)d_in[7];
    const float* W_temp_ui = (const float*)d_in[8];
    const float* W_val_ui  = (const float*)d_in[9];
    const float* att_ui    = (const float*)d_in[10];
    const float* W_src_iu  = (const float*)d_in[11];
    const float* W_dst_iu  = (const float*)d_in[12];
    const float* W_temp_iu = (const float*)d_in[13];
    const float* W_val_iu  = (const float*)d_in[14];
    const float* att_iu    = (const float*)d_in[15];
    const float* Wout_user = (const float*)d_in[16];
    const float* bout_user = (const float*)d_in[17];
    const float* Wout_item = (const float*)d_in[18];
    const float* bout_item = (const float*)d_in[19];
    const float* lnw_user  = (const float*)d_in[20];
    const float* lnb_user  = (const float*)d_in[21];
    const float* lnw_item  = (const float*)d_in[22];
    const float* lnb_item  = (const float*)d_in[23];

    // workspace layout (floats)
    float* agg_item = (float*)d_ws;
    float* agg_user = agg_item + (long)N_NODES * HIDD;
    float* V        = agg_user + (long)N_NODES * HIDD;
    float* sj       = V + (long)N_NODES * HIDD;
    float* si       = sj + (long)N_NODES * 4;
    float* ssum     = si + (long)N_NODES * 4;
    float* exbuf    = ssum + (long)N_NODES * 4;
    // total: 3*6.4M + 3*0.2M + 2M floats = 87.2 MB

    const int nodeBlocks = N_NODES / 16;            // 3125
    const int edgeBlocks = (NE + 255) / 256;        // 1954

    hipMemsetAsync(agg_item, 0, 2 * (size_t)N_NODES * HIDD * sizeof(float), stream);

    // direction ui: src=user, dst=item  -> agg_item
    hipMemsetAsync(ssum, 0, (size_t)N_NODES * 4 * sizeof(float), stream);
    node_proj_kernel<<<nodeBlocks, 256, 0, stream>>>(
        h_user, h_item, W_src_ui, W_dst_ui, W_val_ui, att_ui, sj, si, V);
    edge_logits_kernel<<<edgeBlocks, 256, 0, stream>>>(
        ei_ui, t_ui, W_temp_ui, att_ui, sj, si, exbuf, ssum);
    edge_scatter_kernel<<<edgeBlocks, 256, 0, stream>>>(
        ei_ui, t_ui, W_temp_ui, exbuf, ssum, V, agg_item);

    // direction iu: src=item, dst=user  -> agg_user
    hipMemsetAsync(ssum, 0, (size_t)N_NODES * 4 * sizeof(float), stream);
    node_proj_kernel<<<nodeBlocks, 256, 0, stream>>>(
        h_item, h_user, W_src_iu, W_dst_iu, W_val_iu, att_iu, sj, si, V);
    edge_logits_kernel<<<edgeBlocks, 256, 0, stream>>>(
        ei_iu, t_iu, W_temp_iu, att_iu, sj, si, exbuf, ssum);
    edge_scatter_kernel<<<edgeBlocks, 256, 0, stream>>>(
        ei_iu, t_iu, W_temp_iu, exbuf, ssum, V, agg_user);

    // final: user half then item half of d_out
    float* outp = (float*)d_out;
    out_kernel<<<nodeBlocks, 256, 0, stream>>>(
        agg_user, h_user, Wout_user, bout_user, lnw_user, lnb_user, outp);
    out_kernel<<<nodeBlocks, 256, 0, stream>>>(
        agg_item, h_item, Wout_item, bout_item, lnw_item, lnb_item,
        outp + (long)N_NODES * HIDD);
}

// Round 4
// 1294.958 us; speedup vs baseline: 5.6364x; 5.6364x over previous
//
#include <hip/hip_runtime.h>

#define N_NODES 50000
#define NE      500000
#define HIDD    128
#define TDIM    32
#define NHEAD   4

__device__ __forceinline__ float leaky(float z) { return z >= 0.f ? z : 0.2f * z; }

// ---------------------------------------------------------------------------
// Kernel A: per-node projections for one direction.
//   sj[n][h] = sum_d leaky((x_src@Ws)[n][h,d]) * a_j[h][d]
//   si[n][h] = sum_d leaky((x_dst@Wd)[n][h,d]) * a_i[h][d]
//   V[n][:]  = (x_src@Wv)[n][:]
// ---------------------------------------------------------------------------
__global__ __launch_bounds__(256) void node_proj_kernel(
    const float* __restrict__ xsrc, const float* __restrict__ xdst,
    const float* __restrict__ Ws, const float* __restrict__ Wd,
    const float* __restrict__ Wv, const float* __restrict__ att,
    float* __restrict__ sj, float* __restrict__ si, float* __restrict__ V)
{
    __shared__ float xs[16][HIDD];
    __shared__ float xd[16][HIDD];
    const int t = threadIdx.x;
    const long node0 = (long)blockIdx.x * 16;

    for (int i = 0; i < 8; ++i) {
        int g = t + i * 256;
        int nn = g >> 7, c = g & 127;
        xs[nn][c] = xsrc[(node0 + nn) * HIDD + c];
        xd[nn][c] = xdst[(node0 + nn) * HIDD + c];
    }
    __syncthreads();

    const int c = t & 127;
    const int np = t >> 7;
    const int h = c >> 5, dh = c & 31;

    for (int m = 0; m < 3; ++m) {
        const float* W = (m == 0) ? Ws : ((m == 1) ? Wd : Wv);
        const float (*X)[HIDD] = (m == 1) ? xd : xs;
        float acc[8];
        #pragma unroll
        for (int nn = 0; nn < 8; ++nn) acc[nn] = 0.f;
        for (int k = 0; k < HIDD; ++k) {
            float w = W[k * HIDD + c];
            #pragma unroll
            for (int nn = 0; nn < 8; ++nn) acc[nn] += X[np * 8 + nn][k] * w;
        }
        if (m < 2) {
            float coef = att[h * 96 + (m == 1 ? 32 : 0) + dh];
            float* outp = (m == 0) ? sj : si;
            #pragma unroll
            for (int nn = 0; nn < 8; ++nn) {
                float v = leaky(acc[nn]) * coef;
                #pragma unroll
                for (int off = 16; off > 0; off >>= 1) v += __shfl_down(v, off, 32);
                if (dh == 0) outp[(node0 + np * 8 + nn) * 4 + h] = v;
            }
        } else {
            #pragma unroll
            for (int nn = 0; nn < 8; ++nn)
                V[(node0 + np * 8 + nn) * HIDD + c] = acc[nn];
        }
    }
}

// ---------------------------------------------------------------------------
// CSR build: count -> scan -> scatter indices
// ---------------------------------------------------------------------------
__global__ __launch_bounds__(256) void count_kernel(
    const int* __restrict__ eidst, int* __restrict__ cnt)
{
    int e = blockIdx.x * 256 + threadIdx.x;
    if (e < NE) atomicAdd(&cnt[eidst[e]], 1);
}

#define SCAN_T 1024
#define SCAN_CHUNK 49
__global__ __launch_bounds__(1024) void scan_kernel(
    const int* __restrict__ cnt, int* __restrict__ rowptr)
{
    __shared__ int part[SCAN_T];
    const int t = threadIdx.x;
    const int b = t * SCAN_CHUNK;
    const int e = min(b + SCAN_CHUNK, N_NODES);
    int s = 0;
    for (int i = b; i < e; ++i) s += cnt[i];
    part[t] = s;
    __syncthreads();
    for (int off = 1; off < SCAN_T; off <<= 1) {
        int v = (t >= off) ? part[t - off] : 0;
        __syncthreads();
        part[t] += v;
        __syncthreads();
    }
    int run = (t > 0) ? part[t - 1] : 0;
    for (int i = b; i < e; ++i) { rowptr[i] = run; run += cnt[i]; }
    if (t == SCAN_T - 1) rowptr[N_NODES] = part[SCAN_T - 1];
}

__global__ __launch_bounds__(256) void scatter_idx_kernel(
    const int* __restrict__ eidst, const int* __restrict__ rowptr,
    int* __restrict__ cursor, int* __restrict__ eord)
{
    int e = blockIdx.x * 256 + threadIdx.x;
    if (e < NE) {
        int d = eidst[e];
        int pos = rowptr[d] + atomicAdd(&cursor[d], 1);
        eord[pos] = e;
    }
}

// ---------------------------------------------------------------------------
// Kernel B: per-edge logits + exp. NO atomics (denominator computed in
// gather). 2 edges per thread to amortize LDS WtT reads.
// ---------------------------------------------------------------------------
__global__ __launch_bounds__(256) void edge_logits_kernel(
    const int* __restrict__ ei, const float* __restrict__ tfeat,
    const float* __restrict__ Wt, const float* __restrict__ att,
    const float* __restrict__ sj, const float* __restrict__ si,
    float* __restrict__ exbuf)
{
    __shared__ float WtT[HIDD * TDIM];   // [d][k]
    __shared__ float attL[HIDD];
    const int t = threadIdx.x;
    for (int i = 0; i < 16; ++i) {
        int g = t + i * 256;             // Wt row-major [k][d]
        int k = g >> 7, d = g & 127;
        WtT[d * TDIM + k] = Wt[g];
    }
    if (t < HIDD) attL[t] = att[(t >> 5) * 96 + 64 + (t & 31)];
    __syncthreads();

    const int e0 = blockIdx.x * 512 + t;
    const int e1 = e0 + 256;
    const bool v0 = e0 < NE, v1 = e1 < NE;

    float tt0[TDIM], tt1[TDIM];
    if (v0) {
        const float4* tp = (const float4*)(tfeat + (long)e0 * TDIM);
        #pragma unroll
        for (int i = 0; i < 8; ++i) {
            float4 q = tp[i];
            tt0[4*i] = q.x; tt0[4*i+1] = q.y; tt0[4*i+2] = q.z; tt0[4*i+3] = q.w;
        }
    } else {
        #pragma unroll
        for (int i = 0; i < TDIM; ++i) tt0[i] = 0.f;
    }
    if (v1) {
        const float4* tp = (const float4*)(tfeat + (long)e1 * TDIM);
        #pragma unroll
        for (int i = 0; i < 8; ++i) {
            float4 q = tp[i];
            tt1[4*i] = q.x; tt1[4*i+1] = q.y; tt1[4*i+2] = q.z; tt1[4*i+3] = q.w;
        }
    } else {
        #pragma unroll
        for (int i = 0; i < TDIM; ++i) tt1[i] = 0.f;
    }

    float st0[4] = {0.f,0.f,0.f,0.f}, st1[4] = {0.f,0.f,0.f,0.f};
    for (int d = 0; d < HIDD; ++d) {
        const float4* wp = (const float4*)&WtT[d * TDIM];
        float p0 = 0.f, p1 = 0.f;
        #pragma unroll
        for (int kk = 0; kk < 8; ++kk) {
            float4 w = wp[kk];
            p0 += tt0[kk*4+0]*w.x + tt0[kk*4+1]*w.y + tt0[kk*4+2]*w.z + tt0[kk*4+3]*w.w;
            p1 += tt1[kk*4+0]*w.x + tt1[kk*4+1]*w.y + tt1[kk*4+2]*w.z + tt1[kk*4+3]*w.w;
        }
        float a = attL[d];
        st0[d >> 5] += leaky(p0) * a;
        st1[d >> 5] += leaky(p1) * a;
    }

    if (v0) {
        const int src = ei[e0], dst = ei[NE + e0];
        const float4 sj4 = ((const float4*)sj)[src];
        const float4 si4 = ((const float4*)si)[dst];
        ((float4*)exbuf)[e0] = make_float4(
            __expf(sj4.x + si4.x + st0[0]), __expf(sj4.y + si4.y + st0[1]),
            __expf(sj4.z + si4.z + st0[2]), __expf(sj4.w + si4.w + st0[3]));
    }
    if (v1) {
        const int src = ei[e1], dst = ei[NE + e1];
        const float4 sj4 = ((const float4*)sj)[src];
        const float4 si4 = ((const float4*)si)[dst];
        ((float4*)exbuf)[e1] = make_float4(
            __expf(sj4.x + si4.x + st1[0]), __expf(sj4.y + si4.y + st1[1]),
            __expf(sj4.z + si4.z + st1[2]), __expf(sj4.w + si4.w + st1[3]));
    }
}

// ---------------------------------------------------------------------------
// Kernel C: CSR gather — one wave per dst node, no atomics.
//   agg[dst][d] = sum_e alpha_e[h(d)] V[src_e][d]  +  sum_k U[h(d)][k] Wt[k][d]
//   U[h][k] = sum_e alpha_e[h] tfeat[e][k]   (temporal term factored out)
// Lane l handles dims (2l, 2l+1), both in head h = l>>4.
// ---------------------------------------------------------------------------
__global__ __launch_bounds__(256) void gather_kernel(
    const int* __restrict__ rowptr, const int* __restrict__ eord,
    const int* __restrict__ eisrc, const float* __restrict__ tfeat,
    const float* __restrict__ exbuf, const float* __restrict__ Wt,
    const float* __restrict__ V, float* __restrict__ agg)
{
    __shared__ float WtS[TDIM * HIDD];   // natural [k][d], 16 KB
    __shared__ float ttS[4][TDIM];
    __shared__ float uS[4][HIDD];
    const int t = threadIdx.x;
    for (int i = 0; i < 16; ++i) WtS[t + i * 256] = Wt[t + i * 256];
    __syncthreads();

    const int w = t >> 6, l = t & 63;
    const int dst = blockIdx.x * 4 + w;              // 12500 blocks exactly
    const int h = l >> 4;                            // head of dims 2l,2l+1
    const int k0 = (2 * l) & 31;
    const int beg = rowptr[dst], end = rowptr[dst + 1];

    // pass 1: softmax denominator for this head
    float s = 0.f;
    for (int i = beg; i < end; ++i) s += exbuf[eord[i] * 4 + h];
    const float inv = 1.f / (s + 1e-16f);

    // pass 2: accumulate V part + U
    float acc0 = 0.f, acc1 = 0.f, u0 = 0.f, u1 = 0.f;
    for (int i = beg; i < end; ++i) {
        const int e = eord[i];
        const int src = eisrc[e];
        const float a = exbuf[e * 4 + h] * inv;
        if (l < 32) ttS[w][l] = tfeat[(long)e * TDIM + l];
        __builtin_amdgcn_wave_barrier();
        float2 tk = *(const float2*)&ttS[w][k0];
        float2 vv = *(const float2*)&V[(long)src * HIDD + 2 * l];
        u0 += a * tk.x;  u1 += a * tk.y;
        acc0 += a * vv.x; acc1 += a * vv.y;
        __builtin_amdgcn_wave_barrier();
    }

    // epilogue: temporal contribution via U @ Wt  (U exchange through LDS)
    *(float2*)&uS[w][2 * l] = make_float2(u0, u1);   // index h*32+k == 2l
    __builtin_amdgcn_wave_barrier();
    float t0 = 0.f, t1 = 0.f;
    #pragma unroll
    for (int k = 0; k < TDIM; ++k) {
        float uu = uS[w][h * 32 + k];
        float2 wv = *(const float2*)&WtS[k * HIDD + 2 * l];
        t0 += uu * wv.x;
        t1 += uu * wv.y;
    }
    *(float2*)&agg[(long)dst * HIDD + 2 * l] = make_float2(acc0 + t0, acc1 + t1);
}

// ---------------------------------------------------------------------------
// Kernel D: out = LayerNorm(h + agg @ Wout + bout) * lnw + lnb   (f32 out)
// ---------------------------------------------------------------------------
__global__ __launch_bounds__(256) void out_kernel(
    const float* __restrict__ agg, const float* __restrict__ h,
    const float* __restrict__ Wout, const float* __restrict__ bout,
    const float* __restrict__ lnw, const float* __restrict__ lnb,
    float* __restrict__ out)
{
    __shared__ float ag[16][HIDD];
    __shared__ float red[2][2][2];
    const int t = threadIdx.x;
    const long node0 = (long)blockIdx.x * 16;

    for (int i = 0; i < 8; ++i) {
        int g = t + i * 256;
        int nn = g >> 7, c = g & 127;
        ag[nn][c] = agg[(node0 + nn) * HIDD + c];
    }
    __syncthreads();

    const int c = t & 127;
    const int np = t >> 7;
    const int wg = (t >> 6) & 1;

    float acc[8];
    #pragma unroll
    for (int nn = 0; nn < 8; ++nn) acc[nn] = 0.f;
    for (int k = 0; k < HIDD; ++k) {
        float w = Wout[k * HIDD + c];
        #pragma unroll
        for (int nn = 0; nn < 8; ++nn) acc[nn] += ag[np * 8 + nn][k] * w;
    }

    const float bo = bout[c];
    const float lw = lnw[c];
    const float lb = lnb[c];

    for (int nn = 0; nn < 8; ++nn) {
        long node = node0 + np * 8 + nn;
        float y = h[node * HIDD + c] + acc[nn] + bo;
        float s1 = y, s2 = y * y;
        #pragma unroll
        for (int off = 32; off > 0; off >>= 1) {
            s1 += __shfl_down(s1, off, 64);
            s2 += __shfl_down(s2, off, 64);
        }
        if ((t & 63) == 0) { red[np][wg][0] = s1; red[np][wg][1] = s2; }
        __syncthreads();
        float sum = red[np][0][0] + red[np][1][0];
        float sq  = red[np][0][1] + red[np][1][1];
        float mu  = sum * (1.f / 128.f);
        float var = sq * (1.f / 128.f) - mu * mu;
        float inv = rsqrtf(var + 1e-5f);
        out[node * HIDD + c] = (y - mu) * inv * lw + lb;
        __syncthreads();
    }
}

// ---------------------------------------------------------------------------
extern "C" void kernel_launch(void* const* d_in, const int* in_sizes, int n_in,
                              void* d_out, int out_size, void* d_ws, size_t ws_size,
                              hipStream_t stream)
{
    const float* h_user    = (const float*)d_in[0];
    const float* h_item    = (const float*)d_in[1];
    const int*   ei_ui     = (const int*)d_in[2];
    const float* t_ui      = (const float*)d_in[3];
    const int*   ei_iu     = (const int*)d_in[4];
    const float* t_iu      = (const float*)d_in[5];
    const float* W_src_ui  = (const float*)d_in[6];
    const float* W_dst_ui  = (const float*)d_in[7];
    const float* W_temp_ui = (const float*)d_in[8];
    const float* W_val_ui  = (const float*)d_in[9];
    const float* att_ui    = (const float*)d_in[10];
    const float* W_src_iu  = (const float*)d_in[11];
    const float* W_dst_iu  = (const float*)d_in[12];
    const float* W_temp_iu = (const float*)d_in[13];
    const float* W_val_iu  = (const float*)d_in[14];
    const float* att_iu    = (const float*)d_in[15];
    const float* Wout_user = (const float*)d_in[16];
    const float* bout_user = (const float*)d_in[17];
    const float* Wout_item = (const float*)d_in[18];
    const float* bout_item = (const float*)d_in[19];
    const float* lnw_user  = (const float*)d_in[20];
    const float* lnb_user  = (const float*)d_in[21];
    const float* lnw_item  = (const float*)d_in[22];
    const float* lnb_item  = (const float*)d_in[23];

    // workspace layout
    float* agg_item = (float*)d_ws;
    float* agg_user = agg_item + (long)N_NODES * HIDD;
    float* V        = agg_user + (long)N_NODES * HIDD;
    float* sj       = V + (long)N_NODES * HIDD;
    float* si       = sj + (long)N_NODES * 4;
    float* exbuf    = si + (long)N_NODES * 4;
    int*   rowptr   = (int*)(exbuf + (long)NE * 4);   // N_NODES+1
    int*   cnt      = rowptr + (N_NODES + 8);
    int*   eord     = cnt + N_NODES;
    // total ~ 88.8 MB

    const int nodeBlocks  = N_NODES / 16;             // 3125
    const int edgeBlocks  = (NE + 255) / 256;         // 1954
    const int logitBlocks = (NE + 511) / 512;         // 977
    const int dstBlocks   = N_NODES / 4;              // 12500

    for (int dir = 0; dir < 2; ++dir) {
        const int*   ei    = dir == 0 ? ei_ui : ei_iu;
        const float* tf    = dir == 0 ? t_ui : t_iu;
        const float* xsrc  = dir == 0 ? h_user : h_item;
        const float* xdst  = dir == 0 ? h_item : h_user;
        const float* Ws    = dir == 0 ? W_src_ui : W_src_iu;
        const float* Wd    = dir == 0 ? W_dst_ui : W_dst_iu;
        const float* Wt    = dir == 0 ? W_temp_ui : W_temp_iu;
        const float* Wv    = dir == 0 ? W_val_ui : W_val_iu;
        const float* att   = dir == 0 ? att_ui : att_iu;
        float*       agg   = dir == 0 ? agg_item : agg_user;

        hipMemsetAsync(cnt, 0, N_NODES * sizeof(int), stream);
        count_kernel<<<edgeBlocks, 256, 0, stream>>>(ei + NE, cnt);
        scan_kernel<<<1, SCAN_T, 0, stream>>>(cnt, rowptr);
        hipMemsetAsync(cnt, 0, N_NODES * sizeof(int), stream);
        scatter_idx_kernel<<<edgeBlocks, 256, 0, stream>>>(ei + NE, rowptr, cnt, eord);

        node_proj_kernel<<<nodeBlocks, 256, 0, stream>>>(
            xsrc, xdst, Ws, Wd, Wv, att, sj, si, V);
        edge_logits_kernel<<<logitBlocks, 256, 0, stream>>>(
            ei, tf, Wt, att, sj, si, exbuf);
        gather_kernel<<<dstBlocks, 256, 0, stream>>>(
            rowptr, eord, ei, tf, exbuf, Wt, V, agg);
    }

    float* outp = (float*)d_out;
    out_kernel<<<nodeBlocks, 256, 0, stream>>>(
        agg_user, h_user, Wout_user, bout_user, lnw_user, lnb_user, outp);
    out_kernel<<<nodeBlocks, 256, 0, stream>>>(
        agg_item, h_item, Wout_item, bout_item, lnw_item, lnb_item,
        outp + (long)N_NODES * HIDD);
}

// Round 5
// 1115.943 us; speedup vs baseline: 6.5406x; 1.1604x over previous
//
#include <hip/hip_runtime.h>

#define N_NODES 50000
#define NE      500000
#define HIDD    128
#define TDIM    32

__device__ __forceinline__ float leaky(float z) { return z >= 0.f ? z : 0.2f * z; }

// ---------------------------------------------------------------------------
// Shared helpers for the 128-node/block, 8x8-tile-per-thread fp32 GEMM.
// LDS X layout is XOR-swizzled: row r, source col-quad c4 stored at
// col ((c4 ^ ((r>>3)&3))<<2) so the 8-row fragment reads (b128) are
// bank-conflict-free across the 4 groups in a wave.
// ---------------------------------------------------------------------------
__device__ __forceinline__ void stage128(float (*xs)[HIDD],
                                         const float* __restrict__ x,
                                         int nb, int t)
{
    #pragma unroll
    for (int i = 0; i < 16; ++i) {
        int idx = t + i * 256;              // 0..4095 float4s
        int row = idx >> 5, c4 = idx & 31;
        int col = ((c4 ^ ((row >> 3) & 3)) << 2);
        float4 v = make_float4(0.f, 0.f, 0.f, 0.f);
        if (nb + row < N_NODES)
            v = *(const float4*)&x[(long)(nb + row) * HIDD + c4 * 4];
        *(float4*)&xs[row][col] = v;
    }
}

__device__ __forceinline__ void gemm8x8(const float (*xs)[HIDD],
                                        const float* __restrict__ W,
                                        int g, int c0, float acc[8][8])
{
    #pragma unroll
    for (int a = 0; a < 8; ++a)
        #pragma unroll
        for (int b = 0; b < 8; ++b) acc[a][b] = 0.f;

    for (int k4 = 0; k4 < 32; ++k4) {
        float4 xv[8];
        const int col = ((k4 ^ (g & 3)) << 2);
        #pragma unroll
        for (int nn = 0; nn < 8; ++nn)
            xv[nn] = *(const float4*)&xs[g * 8 + nn][col];
        #pragma unroll
        for (int kk = 0; kk < 4; ++kk) {
            const float4 wa = *(const float4*)&W[(k4 * 4 + kk) * HIDD + c0];
            const float4 wb = *(const float4*)&W[(k4 * 4 + kk) * HIDD + c0 + 4];
            const float wv[8] = {wa.x, wa.y, wa.z, wa.w, wb.x, wb.y, wb.z, wb.w};
            #pragma unroll
            for (int nn = 0; nn < 8; ++nn) {
                const float xk = (kk == 0) ? xv[nn].x : (kk == 1) ? xv[nn].y
                               : (kk == 2) ? xv[nn].z : xv[nn].w;
                #pragma unroll
                for (int j = 0; j < 8; ++j) acc[nn][j] += xk * wv[j];
            }
        }
    }
}

// Per-head attention reduction: p = sum_c leaky(proj[c])*att[h][c&31],
// reduced over the 4 threads (q&3) sharing head h. Writer: q%4==0.
__device__ __forceinline__ void att_reduce_store(
    float acc[8][8], const float* __restrict__ att, int off,
    int nb, int g, int q, int h, float* __restrict__ outp)
{
    const float* ap = att + h * 96 + off + 8 * (q & 3);
    const float4 A0 = *(const float4*)ap, A1 = *(const float4*)(ap + 4);
    const float av[8] = {A0.x, A0.y, A0.z, A0.w, A1.x, A1.y, A1.z, A1.w};
    #pragma unroll
    for (int nn = 0; nn < 8; ++nn) {
        float p = 0.f;
        #pragma unroll
        for (int j = 0; j < 8; ++j) p += leaky(acc[nn][j]) * av[j];
        p += __shfl_down(p, 2, 4);
        p += __shfl_down(p, 1, 4);
        const int node = nb + g * 8 + nn;
        if ((q & 3) == 0 && node < N_NODES) outp[node * 4 + h] = p;
    }
}

// ---------------------------------------------------------------------------
// Kernel A: per-node projections (sj, si, V) — 128 nodes/block.
// ---------------------------------------------------------------------------
__global__ __launch_bounds__(256) void node_proj_kernel(
    const float* __restrict__ xsrc, const float* __restrict__ xdst,
    const float* __restrict__ Ws, const float* __restrict__ Wd,
    const float* __restrict__ Wv, const float* __restrict__ att,
    float* __restrict__ sj, float* __restrict__ si, float* __restrict__ V)
{
    __shared__ float xs[128][HIDD];       // 64 KB
    const int t = threadIdx.x;
    const int g = t >> 4, q = t & 15;
    const int c0 = q * 8, h = q >> 2;
    const int nb = blockIdx.x * 128;

    stage128(xs, xsrc, nb, t);
    __syncthreads();

    {   // m=0: Ws -> sj
        float acc[8][8];
        gemm8x8(xs, Ws, g, c0, acc);
        att_reduce_store(acc, att, 0, nb, g, q, h, sj);
    }
    {   // m=2: Wv -> V
        float acc[8][8];
        gemm8x8(xs, Wv, g, c0, acc);
        #pragma unroll
        for (int nn = 0; nn < 8; ++nn) {
            const int node = nb + g * 8 + nn;
            if (node < N_NODES) {
                *(float4*)&V[(long)node * HIDD + c0] =
                    make_float4(acc[nn][0], acc[nn][1], acc[nn][2], acc[nn][3]);
                *(float4*)&V[(long)node * HIDD + c0 + 4] =
                    make_float4(acc[nn][4], acc[nn][5], acc[nn][6], acc[nn][7]);
            }
        }
    }
    __syncthreads();
    stage128(xs, xdst, nb, t);
    __syncthreads();
    {   // m=1: Wd -> si
        float acc[8][8];
        gemm8x8(xs, Wd, g, c0, acc);
        att_reduce_store(acc, att, 32, nb, g, q, h, si);
    }
}

// ---------------------------------------------------------------------------
// CSR build: count -> scan -> scatter indices
// ---------------------------------------------------------------------------
__global__ __launch_bounds__(256) void count_kernel(
    const int* __restrict__ eidst, int* __restrict__ cnt)
{
    int e = blockIdx.x * 256 + threadIdx.x;
    if (e < NE) atomicAdd(&cnt[eidst[e]], 1);
}

#define SCAN_T 1024
#define SCAN_CHUNK 49
__global__ __launch_bounds__(1024) void scan_kernel(
    const int* __restrict__ cnt, int* __restrict__ rowptr)
{
    __shared__ int part[SCAN_T];
    const int t = threadIdx.x;
    const int b = t * SCAN_CHUNK;
    const int e = min(b + SCAN_CHUNK, N_NODES);
    int s = 0;
    for (int i = b; i < e; ++i) s += cnt[i];
    part[t] = s;
    __syncthreads();
    for (int off = 1; off < SCAN_T; off <<= 1) {
        int v = (t >= off) ? part[t - off] : 0;
        __syncthreads();
        part[t] += v;
        __syncthreads();
    }
    int run = (t > 0) ? part[t - 1] : 0;
    for (int i = b; i < e; ++i) { rowptr[i] = run; run += cnt[i]; }
    if (t == SCAN_T - 1) rowptr[N_NODES] = part[SCAN_T - 1];
}

__global__ __launch_bounds__(256) void scatter_idx_kernel(
    const int* __restrict__ eidst, const int* __restrict__ rowptr,
    int* __restrict__ cursor, int* __restrict__ eord)
{
    int e = blockIdx.x * 256 + threadIdx.x;
    if (e < NE) {
        int d = eidst[e];
        int pos = rowptr[d] + atomicAdd(&cursor[d], 1);
        eord[pos] = e;
    }
}

// ---------------------------------------------------------------------------
// Kernel B: per-edge logits + exp (no atomics). 2 edges/thread.
// ---------------------------------------------------------------------------
__global__ __launch_bounds__(256) void edge_logits_kernel(
    const int* __restrict__ ei, const float* __restrict__ tfeat,
    const float* __restrict__ Wt, const float* __restrict__ att,
    const float* __restrict__ sj, const float* __restrict__ si,
    float* __restrict__ exbuf)
{
    __shared__ float WtT[HIDD * TDIM];   // [d][k]
    __shared__ float attL[HIDD];
    const int t = threadIdx.x;
    for (int i = 0; i < 16; ++i) {
        int g = t + i * 256;             // Wt row-major [k][d]
        int k = g >> 7, d = g & 127;
        WtT[d * TDIM + k] = Wt[g];
    }
    if (t < HIDD) attL[t] = att[(t >> 5) * 96 + 64 + (t & 31)];
    __syncthreads();

    const int e0 = blockIdx.x * 512 + t;
    const int e1 = e0 + 256;
    const bool v0 = e0 < NE, v1 = e1 < NE;

    float tt0[TDIM], tt1[TDIM];
    if (v0) {
        const float4* tp = (const float4*)(tfeat + (long)e0 * TDIM);
        #pragma unroll
        for (int i = 0; i < 8; ++i) {
            float4 qv = tp[i];
            tt0[4*i] = qv.x; tt0[4*i+1] = qv.y; tt0[4*i+2] = qv.z; tt0[4*i+3] = qv.w;
        }
    } else {
        #pragma unroll
        for (int i = 0; i < TDIM; ++i) tt0[i] = 0.f;
    }
    if (v1) {
        const float4* tp = (const float4*)(tfeat + (long)e1 * TDIM);
        #pragma unroll
        for (int i = 0; i < 8; ++i) {
            float4 qv = tp[i];
            tt1[4*i] = qv.x; tt1[4*i+1] = qv.y; tt1[4*i+2] = qv.z; tt1[4*i+3] = qv.w;
        }
    } else {
        #pragma unroll
        for (int i = 0; i < TDIM; ++i) tt1[i] = 0.f;
    }

    float st0[4] = {0.f,0.f,0.f,0.f}, st1[4] = {0.f,0.f,0.f,0.f};
    for (int d = 0; d < HIDD; ++d) {
        const float4* wp = (const float4*)&WtT[d * TDIM];
        float p0 = 0.f, p1 = 0.f;
        #pragma unroll
        for (int kk = 0; kk < 8; ++kk) {
            float4 w = wp[kk];
            p0 += tt0[kk*4+0]*w.x + tt0[kk*4+1]*w.y + tt0[kk*4+2]*w.z + tt0[kk*4+3]*w.w;
            p1 += tt1[kk*4+0]*w.x + tt1[kk*4+1]*w.y + tt1[kk*4+2]*w.z + tt1[kk*4+3]*w.w;
        }
        float a = attL[d];
        st0[d >> 5] += leaky(p0) * a;
        st1[d >> 5] += leaky(p1) * a;
    }

    if (v0) {
        const int src = ei[e0], dst = ei[NE + e0];
        const float4 sj4 = ((const float4*)sj)[src];
        const float4 si4 = ((const float4*)si)[dst];
        ((float4*)exbuf)[e0] = make_float4(
            __expf(sj4.x + si4.x + st0[0]), __expf(sj4.y + si4.y + st0[1]),
            __expf(sj4.z + si4.z + st0[2]), __expf(sj4.w + si4.w + st0[3]));
    }
    if (v1) {
        const int src = ei[e1], dst = ei[NE + e1];
        const float4 sj4 = ((const float4*)sj)[src];
        const float4 si4 = ((const float4*)si)[dst];
        ((float4*)exbuf)[e1] = make_float4(
            __expf(sj4.x + si4.x + st1[0]), __expf(sj4.y + si4.y + st1[1]),
            __expf(sj4.z + si4.z + st1[2]), __expf(sj4.w + si4.w + st1[3]));
    }
}

// ---------------------------------------------------------------------------
// Kernel C: CSR gather — one wave per dst, single pass.
//   agg[dst][d] = (sum_e ex_e[h] (V[src][d]) + (sum_e ex_e[h] t_e) @ Wt) / s_h
// Division folded to the end; no per-edge alpha needed.
// ---------------------------------------------------------------------------
__global__ __launch_bounds__(256) void gather_kernel(
    const int* __restrict__ rowptr, const int* __restrict__ eord,
    const int* __restrict__ eisrc, const float* __restrict__ tfeat,
    const float* __restrict__ exbuf, const float* __restrict__ Wt,
    const float* __restrict__ V, float* __restrict__ agg)
{
    __shared__ float WtS[TDIM * HIDD];   // 16 KB, natural [k][d]
    __shared__ float uS[4][HIDD];
    const int t = threadIdx.x;
    #pragma unroll
    for (int i = 0; i < 4; ++i)
        *(float4*)&WtS[(t + i * 256) * 4] = *(const float4*)&Wt[(t + i * 256) * 4];
    __syncthreads();

    const int w = t >> 6, l = t & 63;
    const int dst = blockIdx.x * 4 + w;              // exact: 12500*4 = 50000
    const int h = l >> 4, d0 = 2 * l, k0 = d0 & 31;
    const int beg = rowptr[dst], end = rowptr[dst + 1];

    float s = 0.f, a0 = 0.f, a1 = 0.f, u0 = 0.f, u1 = 0.f;
    int e_n = 0, s_n = 0;
    if (beg < end) {
        e_n = __builtin_amdgcn_readfirstlane(eord[beg]);
        s_n = __builtin_amdgcn_readfirstlane(eisrc[e_n]);
    }
    for (int i = beg; i < end; ++i) {
        const int e = e_n, src = s_n;
        if (i + 1 < end) {
            e_n = __builtin_amdgcn_readfirstlane(eord[i + 1]);
            s_n = __builtin_amdgcn_readfirstlane(eisrc[e_n]);
        }
        const float  ex = exbuf[e * 4 + h];
        const float2 vv = *(const float2*)&V[(long)src * HIDD + d0];
        const float2 tk = *(const float2*)&tfeat[(long)e * TDIM + k0];
        s  += ex;
        a0 += ex * vv.x;  a1 += ex * vv.y;
        u0 += ex * tk.x;  u1 += ex * tk.y;
    }
    *(float2*)&uS[w][d0] = make_float2(u0, u1);      // (h, k0) lives at idx d0
    __syncthreads();

    const float inv = 1.f / (s + 1e-16f);
    float t0 = 0.f, t1 = 0.f;
    #pragma unroll
    for (int k = 0; k < TDIM; ++k) {
        const float uu = uS[w][h * 32 + k];
        const float2 wv = *(const float2*)&WtS[k * HIDD + d0];
        t0 += uu * wv.x;
        t1 += uu * wv.y;
    }
    *(float2*)&agg[(long)dst * HIDD + d0] =
        make_float2((a0 + t0) * inv, (a1 + t1) * inv);
}

// ---------------------------------------------------------------------------
// Kernel D (fused user+item): out = LN(h + agg@Wout + bout)*lnw + lnb
// 128 nodes/block; LN via shfl over the 16 threads of each node group.
// ---------------------------------------------------------------------------
__global__ __launch_bounds__(256) void out_kernel(
    const float* __restrict__ agg_u, const float* __restrict__ agg_i,
    const float* __restrict__ h_u,   const float* __restrict__ h_i,
    const float* __restrict__ Wo_u,  const float* __restrict__ Wo_i,
    const float* __restrict__ bo_u,  const float* __restrict__ bo_i,
    const float* __restrict__ lw_u,  const float* __restrict__ lw_i,
    const float* __restrict__ lb_u,  const float* __restrict__ lb_i,
    float* __restrict__ out, int nblk)
{
    __shared__ float ag[128][HIDD];      // 64 KB
    const int dir = blockIdx.x >= nblk;
    const int b   = blockIdx.x - dir * nblk;
    const float* agg  = dir ? agg_i : agg_u;
    const float* hx   = dir ? h_i   : h_u;
    const float* Wout = dir ? Wo_i  : Wo_u;
    const float* bout = dir ? bo_i  : bo_u;
    const float* lnw  = dir ? lw_i  : lw_u;
    const float* lnb  = dir ? lb_i  : lb_u;
    float* outp = out + (long)dir * N_NODES * HIDD;

    const int t = threadIdx.x;
    const int g = t >> 4, q = t & 15;
    const int c0 = q * 8;
    const int l = t & 63;
    const int nb = b * 128;

    stage128(ag, agg, nb, t);
    __syncthreads();

    float acc[8][8];
    gemm8x8(ag, Wout, g, c0, acc);

    const float4 B0 = *(const float4*)&bout[c0], B1 = *(const float4*)&bout[c0+4];
    const float4 G0 = *(const float4*)&lnw[c0],  G1 = *(const float4*)&lnw[c0+4];
    const float4 L0 = *(const float4*)&lnb[c0],  L1 = *(const float4*)&lnb[c0+4];
    const float bo[8] = {B0.x,B0.y,B0.z,B0.w,B1.x,B1.y,B1.z,B1.w};
    const float gw[8] = {G0.x,G0.y,G0.z,G0.w,G1.x,G1.y,G1.z,G1.w};
    const float gb[8] = {L0.x,L0.y,L0.z,L0.w,L1.x,L1.y,L1.z,L1.w};

    #pragma unroll
    for (int nn = 0; nn < 8; ++nn) {
        const int node = nb + g * 8 + nn;
        const bool valid = node < N_NODES;
        float y[8];
        float4 H0 = make_float4(0,0,0,0), H1 = make_float4(0,0,0,0);
        if (valid) {
            H0 = *(const float4*)&hx[(long)node * HIDD + c0];
            H1 = *(const float4*)&hx[(long)node * HIDD + c0 + 4];
        }
        const float hv[8] = {H0.x,H0.y,H0.z,H0.w,H1.x,H1.y,H1.z,H1.w};
        float s1 = 0.f, s2 = 0.f;
        #pragma unroll
        for (int j = 0; j < 8; ++j) {
            y[j] = hv[j] + acc[nn][j] + bo[j];
            s1 += y[j];
            s2 += y[j] * y[j];
        }
        s1 += __shfl_down(s1, 8, 16); s2 += __shfl_down(s2, 8, 16);
        s1 += __shfl_down(s1, 4, 16); s2 += __shfl_down(s2, 4, 16);
        s1 += __shfl_down(s1, 2, 16); s2 += __shfl_down(s2, 2, 16);
        s1 += __shfl_down(s1, 1, 16); s2 += __shfl_down(s2, 1, 16);
        s1 = __shfl(s1, l & ~15);
        s2 = __shfl(s2, l & ~15);
        const float mu  = s1 * (1.f / 128.f);
        const float var = s2 * (1.f / 128.f) - mu * mu;
        const float inv = rsqrtf(var + 1e-5f);
        if (valid) {
            float o[8];
            #pragma unroll
            for (int j = 0; j < 8; ++j) o[j] = (y[j] - mu) * inv * gw[j] + gb[j];
            *(float4*)&outp[(long)node * HIDD + c0]     = make_float4(o[0],o[1],o[2],o[3]);
            *(float4*)&outp[(long)node * HIDD + c0 + 4] = make_float4(o[4],o[5],o[6],o[7]);
        }
    }
}

// ---------------------------------------------------------------------------
extern "C" void kernel_launch(void* const* d_in, const int* in_sizes, int n_in,
                              void* d_out, int out_size, void* d_ws, size_t ws_size,
                              hipStream_t stream)
{
    const float* h_user    = (const float*)d_in[0];
    const float* h_item    = (const float*)d_in[1];
    const int*   ei_ui     = (const int*)d_in[2];
    const float* t_ui      = (const float*)d_in[3];
    const int*   ei_iu     = (const int*)d_in[4];
    const float* t_iu      = (const float*)d_in[5];
    const float* W_src_ui  = (const float*)d_in[6];
    const float* W_dst_ui  = (const float*)d_in[7];
    const float* W_temp_ui = (const float*)d_in[8];
    const float* W_val_ui  = (const float*)d_in[9];
    const float* att_ui    = (const float*)d_in[10];
    const float* W_src_iu  = (const float*)d_in[11];
    const float* W_dst_iu  = (const float*)d_in[12];
    const float* W_temp_iu = (const float*)d_in[13];
    const float* W_val_iu  = (const float*)d_in[14];
    const float* att_iu    = (const float*)d_in[15];
    const float* Wout_user = (const float*)d_in[16];
    const float* bout_user = (const float*)d_in[17];
    const float* Wout_item = (const float*)d_in[18];
    const float* bout_item = (const float*)d_in[19];
    const float* lnw_user  = (const float*)d_in[20];
    const float* lnb_user  = (const float*)d_in[21];
    const float* lnw_item  = (const float*)d_in[22];
    const float* lnb_item  = (const float*)d_in[23];

    // workspace layout (same footprint as the passing R4 layout)
    float* agg_item = (float*)d_ws;
    float* agg_user = agg_item + (long)N_NODES * HIDD;
    float* V        = agg_user + (long)N_NODES * HIDD;
    float* sj       = V + (long)N_NODES * HIDD;
    float* si       = sj + (long)N_NODES * 4;
    float* exbuf    = si + (long)N_NODES * 4;
    int*   rowptr   = (int*)(exbuf + (long)NE * 4);   // N_NODES+1
    int*   cnt      = rowptr + (N_NODES + 8);
    int*   eord     = cnt + N_NODES;

    const int edgeBlocks  = (NE + 255) / 256;         // 1954
    const int logitBlocks = (NE + 511) / 512;         // 977
    const int dstBlocks   = N_NODES / 4;              // 12500
    const int projBlocks  = (N_NODES + 127) / 128;    // 391

    for (int dir = 0; dir < 2; ++dir) {
        const int*   ei   = dir == 0 ? ei_ui : ei_iu;
        const float* tf   = dir == 0 ? t_ui : t_iu;
        const float* xsrc = dir == 0 ? h_user : h_item;
        const float* xdst = dir == 0 ? h_item : h_user;
        const float* Ws   = dir == 0 ? W_src_ui : W_src_iu;
        const float* Wd   = dir == 0 ? W_dst_ui : W_dst_iu;
        const float* Wt   = dir == 0 ? W_temp_ui : W_temp_iu;
        const float* Wv   = dir == 0 ? W_val_ui : W_val_iu;
        const float* att  = dir == 0 ? att_ui : att_iu;
        float*       agg  = dir == 0 ? agg_item : agg_user;

        hipMemsetAsync(cnt, 0, N_NODES * sizeof(int), stream);
        count_kernel<<<edgeBlocks, 256, 0, stream>>>(ei + NE, cnt);
        scan_kernel<<<1, SCAN_T, 0, stream>>>(cnt, rowptr);
        hipMemsetAsync(cnt, 0, N_NODES * sizeof(int), stream);
        scatter_idx_kernel<<<edgeBlocks, 256, 0, stream>>>(ei + NE, rowptr, cnt, eord);

        node_proj_kernel<<<projBlocks, 256, 0, stream>>>(
            xsrc, xdst, Ws, Wd, Wv, att, sj, si, V);
        edge_logits_kernel<<<logitBlocks, 256, 0, stream>>>(
            ei, tf, Wt, att, sj, si, exbuf);
        gather_kernel<<<dstBlocks, 256, 0, stream>>>(
            rowptr, eord, ei, tf, exbuf, Wt, V, agg);
    }

    out_kernel<<<2 * projBlocks, 256, 0, stream>>>(
        agg_user, agg_item, h_user, h_item,
        Wout_user, Wout_item, bout_user, bout_item,
        lnw_user, lnw_item, lnb_user, lnb_item,
        (float*)d_out, projBlocks);
}